// Round 17
// baseline (353.076 us; speedup 1.0000x reference)
//
#include <hip/hip_runtime.h>
#include <math.h>

#define SIG_L 128000
#define NBATCH 64
#define NROWS 257
#define HOP 128
#define NUMF 999
#define NFRM 30
#define NWIN 969
#define NB_MAX 16
#define FBINS 160          // kmap entries (>= 144 used bins)
#define TILES 9            // M = 288 rows = 144 bins x (re,im)
#define KSTEPS 16
#define FPBX 256           // frames per block (four 64-columns)
#define NTX 4              // ceil(999/256)
#define AKB 18432          // bytes per A kk-chunk (9 tiles x 2 planes x 1024B)
#define BCH 4112           // B 16-byte chunks: (255*128+256)/8 = 4112
#define BETA_F 6.623413251903491f  // 1 + 10^(15/20)

typedef __attribute__((ext_vector_type(8))) short short8;
typedef __attribute__((ext_vector_type(16))) float f32x16;
typedef unsigned short ushort_t;

// RNE split of fp32 into bf16 hi + bf16 lo (hi RNE; rem = v - hi exact in fp32)
__device__ inline ushort_t bf_hi_rne(float v, float* rem) {
    unsigned u = __float_as_uint(v);
    unsigned hr = (u + 0x7FFFu + ((u >> 16) & 1u)) & 0xFFFF0000u;
    *rem = v - __uint_as_float(hr);
    return (ushort_t)(hr >> 16);
}
__device__ inline ushort_t bf_rne(float v) {
    unsigned u = __float_as_uint(v);
    return (ushort_t)((u + 0x7FFFu + ((u >> 16) & 1u)) >> 16);
}

__device__ inline void gll16(const void* g, void* l) {
    __builtin_amdgcn_global_load_lds(
        (const __attribute__((address_space(1))) unsigned int*)g,
        (__attribute__((address_space(3))) unsigned int*)l, 16, 0, 0);
}

// DCE keeper: keep a loaded b128 value alive without using it (rule #17)
__device__ inline void keep8(const short8& v) {
    const int* p = (const int*)&v;
    asm volatile("" :: "v"(p[0]), "v"(p[1]), "v"(p[2]), "v"(p[3]));
}

// ---------- K0: octmat scan -> hdr[32+f] = band id of bin f (or -1) ----------
__global__ void k_scan(const float* __restrict__ oct, int NB, int* __restrict__ hdr) {
    __shared__ int smin[16], smax[16];
    int tid = threadIdx.x;
    if (tid < NB) { smin[tid] = 0x7fffffff; smax[tid] = -1; }
    __syncthreads();
    for (int idx = tid; idx < NB * NROWS; idx += blockDim.x) {
        int k = idx / NROWS, f = idx % NROWS;
        if (oct[idx] != 0.0f) { atomicMin(&smin[k], f); atomicMax(&smax[k], f); }
    }
    __syncthreads();
    if (tid < FBINS) {
        int kid = -1;
        for (int k = 0; k < NB; ++k)
            if (smax[k] >= 0 && tid >= smin[k] && tid <= smax[k]) kid = k;
        hdr[32 + tid] = kid;
    }
}

// ---------- K0b: weight pack, fragment order, kk-chunked ----------
__global__ void k_prep(const float* __restrict__ fftmat, ushort_t* __restrict__ wpack) {
    for (int u = 0; u < 2; ++u) {
        int idx = blockIdx.x * 512 + u * 256 + threadIdx.x;   // < 147456
        int e = idx & 7, l = (idx >> 3) & 63, p = (idx >> 9) & 1;
        int tt = (idx >> 10) % TILES, kk = (idx >> 10) / TILES;
        int row32 = l & 31, kq = l >> 5;
        int bin = tt * 16 + (row32 >> 1);
        int part = row32 & 1;
        int k = kk * 16 + kq * 8 + e;
        float v = fftmat[(size_t)(part ? (NROWS + bin) : bin) * 512 + 128 + k];
        float rem; ushort_t hb = bf_hi_rne(v, &rem);
        wpack[idx] = p ? bf_rne(rem) : hb;
    }
}

// ---------- K1: r15 kernel, templated for ablation ----------
// V=0 full (correct; launched LAST).  V=1 no MFMA.  V=2 no A-staging.
// V=3 no B ds_reads.  V=4 no in-loop barriers + no A-staging (pure core).
template <int V>
__global__ __launch_bounds__(768, 3) void k_stft(
    const float* __restrict__ targ, const float* __restrict__ pred,
    const ushort_t* __restrict__ wpack, const int* __restrict__ hdr,
    float* __restrict__ xbuf, float* __restrict__ ybuf, int NB) {
    __shared__ __align__(16) char smem[2 * AKB + BCH * 16 + NB_MAX * FPBX * 4 + 640];
    ushort_t* As    = (ushort_t*)smem;
    char*     Bs    = smem + 2 * AKB;
    float*    bacc  = (float*)(smem + 2 * AKB + BCH * 16);
    int*      kmapS = (int*)(smem + 2 * AKB + BCH * 16 + NB_MAX * FPBX * 4);

    const int tid = threadIdx.x;
    const int lane = tid & 63;
    const int wv = __builtin_amdgcn_readfirstlane(tid >> 6); // 0..11
    const int mg  = wv >> 2;
    const int col = wv & 3;
    const int tbase = mg * 3;
    const int b = blockIdx.y, z = blockIdx.z;
    const int t0 = blockIdx.x * FPBX;
    const float* __restrict__ sig = z ? pred : targ;
    float* __restrict__ out = z ? ybuf : xbuf;
    const size_t boff = (size_t)b * SIG_L;

    for (int i = tid; i < NB_MAX * FPBX; i += 768) bacc[i] = 0.0f;
    for (int i = tid; i < FBINS; i += 768) kmapS[i] = hdr[32 + i];

    // ---- B stage: raw signal -> bf16, XOR-swizzled 16B chunks ----
    const long sbase = (long)t0 * HOP;
    for (int c = tid; c < BCH; c += 768) {
        const long g0 = sbase + (long)c * 8;
        float v[8];
        if (g0 + 8 <= SIG_L) {
            float4 x0 = *(const float4*)(sig + boff + g0);
            float4 x1 = *(const float4*)(sig + boff + g0 + 4);
            v[0] = x0.x; v[1] = x0.y; v[2] = x0.z; v[3] = x0.w;
            v[4] = x1.x; v[5] = x1.y; v[6] = x1.z; v[7] = x1.w;
        } else {
#pragma unroll
            for (int e = 0; e < 8; ++e)
                v[e] = (g0 + e < SIG_L) ? sig[boff + g0 + e] : 0.0f;
        }
        short8 sv;
#pragma unroll
        for (int e = 0; e < 8; ++e) sv[e] = (short)bf_rne(v[e]);
        int byte = c * 16;
        byte ^= ((byte >> 8) & 0xF) << 4;
        *(short8*)(Bs + byte) = sv;
    }
    if (V == 3) {   // keep B-stage live though never read
        short8 kv = *(const short8*)(Bs + (tid & 1023) * 16);
        keep8(kv);
    }
    // ---- A stage kk=0 ----
    if (V != 2 && V != 4) {
        const char* gsrc = (const char*)wpack;
        for (int j = wv; j < 18; j += 12)
            gll16(gsrc + j * 1024 + lane * 16, smem + j * 1024);
    }
    __syncthreads();

    f32x16 acc[3][2];
#pragma unroll
    for (int g = 0; g < 3; ++g)
#pragma unroll
        for (int bt = 0; bt < 2; ++bt)
#pragma unroll
            for (int e = 0; e < 16; ++e) acc[g][bt][e] = 0.0f;

    const int jloc = lane & 31, kq = lane >> 5;

    int cur = 0;
#pragma unroll 1
    for (int kk = 0; kk < KSTEPS; ++kk) {
        if (V != 2 && V != 4) {
            if (kk < KSTEPS - 1) {
                const char* gsrc = (const char*)wpack + (size_t)(kk + 1) * AKB;
                char* ldst = smem + (cur ^ 1) * AKB;
                for (int j = wv; j < 18; j += 12)
                    gll16(gsrc + j * 1024 + lane * 16, ldst + j * 1024);
            }
        }
        // B fragments
        short8 S[2];
        if (V != 3) {
#pragma unroll
            for (int bt = 0; bt < 2; ++bt) {
                const int fl = col * 64 + bt * 32 + jloc;
                int byte = fl * 256 + kk * 32 + kq * 16;
                byte ^= ((byte >> 8) & 0xF) << 4;
                S[bt] = *(const short8*)(Bs + byte);
            }
            if (V == 1) { keep8(S[0]); keep8(S[1]); }
        } else {
#pragma unroll
            for (int bt = 0; bt < 2; ++bt)
#pragma unroll
                for (int e = 0; e < 8; ++e) S[bt][e] = (short)0x3f80;
        }
        const ushort_t* ab = As + cur * (AKB / 2) + tbase * 1024 + lane * 8;
        if (V == 1) {
#pragma unroll
            for (int g = 0; g < 3; ++g) {
                short8 Ah = *(const short8*)(ab + g * 1024);
                short8 Al = *(const short8*)(ab + g * 1024 + 512);
                keep8(Ah); keep8(Al);
            }
        } else {
            __builtin_amdgcn_s_setprio(1);
#pragma unroll
            for (int g = 0; g < 3; ++g) {
                short8 Ah = *(const short8*)(ab + g * 1024);
                short8 Al = *(const short8*)(ab + g * 1024 + 512);
                acc[g][0] = __builtin_amdgcn_mfma_f32_32x32x16_bf16(Ah, S[0], acc[g][0], 0, 0, 0);
                acc[g][1] = __builtin_amdgcn_mfma_f32_32x32x16_bf16(Ah, S[1], acc[g][1], 0, 0, 0);
                acc[g][0] = __builtin_amdgcn_mfma_f32_32x32x16_bf16(Al, S[0], acc[g][0], 0, 0, 0);
                acc[g][1] = __builtin_amdgcn_mfma_f32_32x32x16_bf16(Al, S[1], acc[g][1], 0, 0, 0);
            }
            __builtin_amdgcn_s_setprio(0);
        }
        if (V != 4) __syncthreads();
        cur ^= 1;
    }

    // ---- epilogue: energies -> band accumulate -> global ----
    if (V == 4) __syncthreads();
#pragma unroll
    for (int g = 0; g < 3; ++g) {
#pragma unroll
        for (int bt = 0; bt < 2; ++bt) {
            const int fl = col * 64 + bt * 32 + jloc;
            float run = 0.0f; int runk = -1;
#pragma unroll
            for (int rr = 0; rr < 8; ++rr) {
                const int m = (rr & 1) + 4 * (rr >> 1) + 2 * kq;
                const int kid = kmapS[(tbase + g) * 16 + m];
                const float vr = acc[g][bt][rr * 2], vi = acc[g][bt][rr * 2 + 1];
                const float e = vr * vr + vi * vi;
                if (kid != runk) {
                    if (runk >= 0) atomicAdd(&bacc[runk * FPBX + fl], run);
                    run = 0.0f; runk = kid;
                }
                if (kid >= 0) run += e;
            }
            if (runk >= 0) atomicAdd(&bacc[runk * FPBX + fl], run);
        }
    }
    __syncthreads();
    for (int idx = tid; idx < NB * FPBX; idx += 768) {
        int k = idx >> 8, t = idx & (FPBX - 1);
        int tg = t0 + t;
        if (tg < NUMF)
            out[((size_t)b * NB + k) * NUMF + tg] = bacc[k * FPBX + t];
    }
}

// ---------- K2: sliding-window correlations (reads energies, applies sqrt) ----------
__global__ __launch_bounds__(256) void k_corr(const float* __restrict__ xbuf,
                                              const float* __restrict__ ybuf,
                                              int NB, double* __restrict__ partials) {
    const int k = blockIdx.x, b = blockIdx.y;
    const long roff = ((long)b * NB + k) * NUMF;
    __shared__ float xl[NUMF], yl[NUMF];
    __shared__ double red[256];
    const int tid = threadIdx.x;
    for (int i = tid; i < NUMF; i += 256) {
        xl[i] = sqrtf(xbuf[roff + i]);
        yl[i] = sqrtf(ybuf[roff + i]);
    }
    __syncthreads();
    double loc = 0.0;
    for (int w = tid; w < NWIN; w += 256) {
        float sx = 0, sxx = 0, syy = 0;
        for (int i = 0; i < NFRM; ++i) {
            float xv = xl[w + i], yv = yl[w + i];
            sx += xv; sxx += xv * xv; syy += yv * yv;
        }
        float alpha = sqrtf(sxx / (syy + 1e-7f));
        float sy = 0;
        for (int i = 0; i < NFRM; ++i)
            sy += fminf(alpha * yl[w + i], BETA_F * xl[w + i]);
        float mx = sx * (1.0f / NFRM), my = sy * (1.0f / NFRM);
        float cxx = 0, cyy = 0, cxy = 0;
        for (int i = 0; i < NFRM; ++i) {
            float dx = xl[w + i] - mx;
            float dy = fminf(alpha * yl[w + i], BETA_F * xl[w + i]) - my;
            cxx += dx * dx; cyy += dy * dy; cxy += dx * dy;
        }
        loc += (double)cxy / sqrt((double)cxx * (double)cyy);
    }
    red[tid] = loc;
    __syncthreads();
    for (int s = 128; s > 0; s >>= 1) {
        if (tid < s) red[tid] += red[tid + s];
        __syncthreads();
    }
    if (tid == 0) partials[b * NB + k] = red[0];
}

// ---------- K3: final deterministic reduction ----------
__global__ void k_final(const double* __restrict__ partials, int NB, float* __restrict__ out) {
    __shared__ double red[256];
    const int tid = threadIdx.x;
    const int n = NBATCH * NB;
    double s = 0.0;
    for (int i = tid; i < n; i += 256) s += partials[i];
    red[tid] = s;
    __syncthreads();
    for (int st = 128; st > 0; st >>= 1) {
        if (tid < st) red[tid] += red[tid + st];
        __syncthreads();
    }
    if (tid == 0) out[0] = (float)(-red[0] / ((double)NBATCH * NB * NWIN));
}

extern "C" void kernel_launch(void* const* d_in, const int* in_sizes, int n_in,
                              void* d_out, int out_size, void* d_ws, size_t ws_size,
                              hipStream_t stream) {
    const float* pred   = (const float*)d_in[0];
    const float* targ   = (const float*)d_in[1];
    const float* fftmat = (const float*)d_in[3];
    const float* oct    = (const float*)d_in[4];
    const int NB = in_sizes[4] / NROWS;   // 15

    char* ws = (char*)d_ws;
    int*      hdr   = (int*)ws;                          // 1 KB
    ushort_t* wpack = (ushort_t*)(ws + 1024);            // 147456 shorts = 294912 B
    size_t o1 = 1024 + (size_t)KSTEPS * TILES * 2 * 512 * 2;
    size_t xsz = (size_t)NBATCH * NB_MAX * NUMF * 4;
    float*  xbuf = (float*)(ws + o1);
    float*  ybuf = (float*)(ws + o1 + xsz);
    double* partials = (double*)(ws + o1 + 2 * xsz);

    dim3 g(NTX, NBATCH, 2), blk(768);
    hipLaunchKernelGGL(k_scan, dim3(1), dim3(256), 0, stream, oct, NB, hdr);
    hipLaunchKernelGGL(k_prep, dim3(288), dim3(256), 0, stream, fftmat, wpack);
    // ---- ablation variants (outputs overwritten by V0 below) ----
    hipLaunchKernelGGL((k_stft<1>), g, blk, 0, stream, targ, pred, wpack, hdr, xbuf, ybuf, NB);
    hipLaunchKernelGGL((k_stft<2>), g, blk, 0, stream, targ, pred, wpack, hdr, xbuf, ybuf, NB);
    hipLaunchKernelGGL((k_stft<3>), g, blk, 0, stream, targ, pred, wpack, hdr, xbuf, ybuf, NB);
    hipLaunchKernelGGL((k_stft<4>), g, blk, 0, stream, targ, pred, wpack, hdr, xbuf, ybuf, NB);
    // ---- the real one (correct, last) ----
    hipLaunchKernelGGL((k_stft<0>), g, blk, 0, stream, targ, pred, wpack, hdr, xbuf, ybuf, NB);
    hipLaunchKernelGGL(k_corr, dim3(NB, NBATCH), dim3(256), 0, stream, xbuf, ybuf, NB, partials);
    hipLaunchKernelGGL(k_final, dim3(1), dim3(256), 0, stream, partials, NB, (float*)d_out);
}

// Round 18
// 105.658 us; speedup vs baseline: 3.3417x; 3.3417x over previous
//
#include <hip/hip_runtime.h>
#include <math.h>

#define SIG_L 128000
#define NBATCH 64
#define NROWS 257
#define HOP 128
#define NUMF 999
#define NFRM 30
#define NWIN 969
#define NB_MAX 16
#define FBINS 160          // kmap entries (>= 144 used bins)
#define TILES 9            // M = 288 rows = 144 bins x (re,im)
#define KSTEPS 16
#define FPBX 256           // frames per task (four 64-columns)
#define AKB 18432          // bytes per A kk-chunk (9 tiles x 2 planes x 1024B)
#define BCH 4112           // B 16-byte chunks: (255*128+256)/8 = 4112
#define SMEMSZ (2 * AKB + BCH * 16 + NB_MAX * FPBX * 4 + 640)
#define BETA_F 6.623413251903491f  // 1 + 10^(15/20)

typedef __attribute__((ext_vector_type(8))) short short8;
typedef __attribute__((ext_vector_type(16))) float f32x16;
typedef unsigned short ushort_t;

// RNE split of fp32 into bf16 hi + bf16 lo (hi RNE; rem = v - hi exact in fp32)
__device__ inline ushort_t bf_hi_rne(float v, float* rem) {
    unsigned u = __float_as_uint(v);
    unsigned hr = (u + 0x7FFFu + ((u >> 16) & 1u)) & 0xFFFF0000u;
    *rem = v - __uint_as_float(hr);
    return (ushort_t)(hr >> 16);
}
__device__ inline ushort_t bf_rne(float v) {
    unsigned u = __float_as_uint(v);
    return (ushort_t)((u + 0x7FFFu + ((u >> 16) & 1u)) >> 16);
}

__device__ inline void gll16(const void* g, void* l) {
    __builtin_amdgcn_global_load_lds(
        (const __attribute__((address_space(1))) unsigned int*)g,
        (__attribute__((address_space(3))) unsigned int*)l, 16, 0, 0);
}

// ---------- K0: octmat scan -> hdr[32+f] = band id of bin f (or -1) ----------
__global__ void k_scan(const float* __restrict__ oct, int NB, int* __restrict__ hdr) {
    __shared__ int smin[16], smax[16];
    int tid = threadIdx.x;
    if (tid < NB) { smin[tid] = 0x7fffffff; smax[tid] = -1; }
    __syncthreads();
    for (int idx = tid; idx < NB * NROWS; idx += blockDim.x) {
        int k = idx / NROWS, f = idx % NROWS;
        if (oct[idx] != 0.0f) { atomicMin(&smin[k], f); atomicMax(&smax[k], f); }
    }
    __syncthreads();
    if (tid < FBINS) {
        int kid = -1;
        for (int k = 0; k < NB; ++k)
            if (smax[k] >= 0 && tid >= smin[k] && tid <= smax[k]) kid = k;
        hdr[32 + tid] = kid;
    }
}

// ---------- K0b: weight pack, fragment order, kk-chunked ----------
__global__ void k_prep(const float* __restrict__ fftmat, ushort_t* __restrict__ wpack) {
    for (int u = 0; u < 2; ++u) {
        int idx = blockIdx.x * 512 + u * 256 + threadIdx.x;   // < 147456
        int e = idx & 7, l = (idx >> 3) & 63, p = (idx >> 9) & 1;
        int tt = (idx >> 10) % TILES, kk = (idx >> 10) / TILES;
        int row32 = l & 31, kq = l >> 5;
        int bin = tt * 16 + (row32 >> 1);
        int part = row32 & 1;
        int k = kk * 16 + kq * 8 + e;
        float v = fftmat[(size_t)(part ? (NROWS + bin) : bin) * 512 + 128 + k];
        float rem; ushort_t hb = bf_hi_rne(v, &rem);
        wpack[idx] = p ? bf_rne(rem) : hb;
    }
}

// ---------- Probe: measures fixed per-block cost F (512 big-LDS blocks, no work) ----------
__global__ __launch_bounds__(768, 3) void k_probe(float* sink) {
    __shared__ __align__(16) char smem[SMEMSZ];
    float* bacc = (float*)smem;
    const int tid = threadIdx.x;
    for (int i = tid; i < 4096; i += 768) bacc[i] = 0.0f;
    __syncthreads();
    float v = bacc[(tid * 37 + 1) & 4095];
    asm volatile("" :: "v"(v));
    (void)sink;
}

// ---------- K1: persistent MFMA STFT (2 tasks/block), max-MLP staging ----------
// grid 256 (1 block/CU). Task t = bx + 256*i -> (z, b, tile). Per task: r15 body.
// B = raw signal bf16 LDS, XOR swizzle (0 conflicts). A = LDS dbuf via gll16.
// 2-term numerics (absmax 3.05e-5, proven).
__global__ __launch_bounds__(768, 3) void k_stft(
    const float* __restrict__ targ, const float* __restrict__ pred,
    const ushort_t* __restrict__ wpack, const int* __restrict__ hdr,
    float* __restrict__ xbuf, float* __restrict__ ybuf, int NB) {
    __shared__ __align__(16) char smem[SMEMSZ];
    ushort_t* As    = (ushort_t*)smem;
    char*     Bs    = smem + 2 * AKB;
    float*    bacc  = (float*)(smem + 2 * AKB + BCH * 16);
    int*      kmapS = (int*)(smem + 2 * AKB + BCH * 16 + NB_MAX * FPBX * 4);

    const int tid = threadIdx.x;
    const int lane = tid & 63;
    const int wv = __builtin_amdgcn_readfirstlane(tid >> 6); // 0..11
    const int mg  = wv >> 2;
    const int col = wv & 3;
    const int tbase = mg * 3;
    const int jloc = lane & 31, kq = lane >> 5;

    for (int i = tid; i < FBINS; i += 768) kmapS[i] = hdr[32 + i];

#pragma unroll 1
    for (int task = 0; task < 2; ++task) {
        const int t = (int)blockIdx.x + 256 * task;
        const int z = t & 1, b = (t >> 1) & 63, tile = (t >> 7) & 3;
        const int t0 = tile * FPBX;
        const float* __restrict__ sig = z ? pred : targ;
        float* __restrict__ out = z ? ybuf : xbuf;
        const size_t boff = (size_t)b * SIG_L;

        if (task) __syncthreads();          // prior task fully done with smem
        for (int i = tid; i < NB_MAX * FPBX; i += 768) bacc[i] = 0.0f;

        // ---- B stage: 12 loads issued up-front (branchless), then cvt+swz writes
        const long sbase = (long)t0 * HOP;
        float4 xr[12];
#pragma unroll
        for (int u = 0; u < 6; ++u) {
            const int c = tid + u * 768;
            const long g0 = sbase + (long)c * 8;
            const bool full = (c < BCH) && (g0 + 8 <= SIG_L);
            const long gc = full ? g0 : 0;   // clamp: always-valid address
            const float* p = sig + boff + gc;
            float4 a0 = *(const float4*)(p);
            float4 a1 = *(const float4*)(p + 4);
            if (!full) { a0 = (float4){0,0,0,0}; a1 = (float4){0,0,0,0}; }
            xr[2*u] = a0; xr[2*u+1] = a1;
        }
#pragma unroll
        for (int u = 0; u < 6; ++u) {
            const int c = tid + u * 768;
            if (c < BCH) {
                short8 sv;
                sv[0]=(short)bf_rne(xr[2*u].x);   sv[1]=(short)bf_rne(xr[2*u].y);
                sv[2]=(short)bf_rne(xr[2*u].z);   sv[3]=(short)bf_rne(xr[2*u].w);
                sv[4]=(short)bf_rne(xr[2*u+1].x); sv[5]=(short)bf_rne(xr[2*u+1].y);
                sv[6]=(short)bf_rne(xr[2*u+1].z); sv[7]=(short)bf_rne(xr[2*u+1].w);
                int byte = c * 16;
                byte ^= ((byte >> 8) & 0xF) << 4;
                *(short8*)(Bs + byte) = sv;
            }
        }
        // ---- A stage kk=0 into As[0] ----
        {
            const char* gsrc = (const char*)wpack;
            for (int j = wv; j < 18; j += 12)
                gll16(gsrc + j * 1024 + lane * 16, smem + j * 1024);
        }
        __syncthreads();

        f32x16 acc[3][2];
#pragma unroll
        for (int g = 0; g < 3; ++g)
#pragma unroll
            for (int bt = 0; bt < 2; ++bt)
#pragma unroll
                for (int e = 0; e < 16; ++e) acc[g][bt][e] = 0.0f;

        int cur = 0;
#pragma unroll 1
        for (int kk = 0; kk < KSTEPS; ++kk) {
            if (kk < KSTEPS - 1) {
                const char* gsrc = (const char*)wpack + (size_t)(kk + 1) * AKB;
                char* ldst = smem + (cur ^ 1) * AKB;
                for (int j = wv; j < 18; j += 12)
                    gll16(gsrc + j * 1024 + lane * 16, ldst + j * 1024);
            }
            short8 S[2];
#pragma unroll
            for (int bt = 0; bt < 2; ++bt) {
                const int fl = col * 64 + bt * 32 + jloc;
                int byte = fl * 256 + kk * 32 + kq * 16;
                byte ^= ((byte >> 8) & 0xF) << 4;
                S[bt] = *(const short8*)(Bs + byte);
            }
            const ushort_t* ab = As + cur * (AKB / 2) + tbase * 1024 + lane * 8;
            __builtin_amdgcn_s_setprio(1);
#pragma unroll
            for (int g = 0; g < 3; ++g) {
                short8 Ah = *(const short8*)(ab + g * 1024);
                short8 Al = *(const short8*)(ab + g * 1024 + 512);
                acc[g][0] = __builtin_amdgcn_mfma_f32_32x32x16_bf16(Ah, S[0], acc[g][0], 0, 0, 0);
                acc[g][1] = __builtin_amdgcn_mfma_f32_32x32x16_bf16(Ah, S[1], acc[g][1], 0, 0, 0);
                acc[g][0] = __builtin_amdgcn_mfma_f32_32x32x16_bf16(Al, S[0], acc[g][0], 0, 0, 0);
                acc[g][1] = __builtin_amdgcn_mfma_f32_32x32x16_bf16(Al, S[1], acc[g][1], 0, 0, 0);
            }
            __builtin_amdgcn_s_setprio(0);
            __syncthreads();
            cur ^= 1;
        }

        // ---- epilogue: energies -> band accumulate -> global ----
#pragma unroll
        for (int g = 0; g < 3; ++g) {
#pragma unroll
            for (int bt = 0; bt < 2; ++bt) {
                const int fl = col * 64 + bt * 32 + jloc;
                float run = 0.0f; int runk = -1;
#pragma unroll
                for (int rr = 0; rr < 8; ++rr) {
                    const int m = (rr & 1) + 4 * (rr >> 1) + 2 * kq;
                    const int kid = kmapS[(tbase + g) * 16 + m];
                    const float vr = acc[g][bt][rr * 2], vi = acc[g][bt][rr * 2 + 1];
                    const float e = vr * vr + vi * vi;
                    if (kid != runk) {
                        if (runk >= 0) atomicAdd(&bacc[runk * FPBX + fl], run);
                        run = 0.0f; runk = kid;
                    }
                    if (kid >= 0) run += e;
                }
                if (runk >= 0) atomicAdd(&bacc[runk * FPBX + fl], run);
            }
        }
        __syncthreads();
        for (int idx = tid; idx < NB * FPBX; idx += 768) {
            int k = idx >> 8, tt = idx & (FPBX - 1);
            int tg = t0 + tt;
            if (tg < NUMF)
                out[((size_t)b * NB + k) * NUMF + tg] = bacc[k * FPBX + tt];
        }
    }
}

// ---------- K2: sliding-window correlations (reads energies, applies sqrt) ----------
__global__ __launch_bounds__(256) void k_corr(const float* __restrict__ xbuf,
                                              const float* __restrict__ ybuf,
                                              int NB, double* __restrict__ partials) {
    const int k = blockIdx.x, b = blockIdx.y;
    const long roff = ((long)b * NB + k) * NUMF;
    __shared__ float xl[NUMF], yl[NUMF];
    __shared__ double red[256];
    const int tid = threadIdx.x;
    for (int i = tid; i < NUMF; i += 256) {
        xl[i] = sqrtf(xbuf[roff + i]);
        yl[i] = sqrtf(ybuf[roff + i]);
    }
    __syncthreads();
    double loc = 0.0;
    for (int w = tid; w < NWIN; w += 256) {
        float sx = 0, sxx = 0, syy = 0;
        for (int i = 0; i < NFRM; ++i) {
            float xv = xl[w + i], yv = yl[w + i];
            sx += xv; sxx += xv * xv; syy += yv * yv;
        }
        float alpha = sqrtf(sxx / (syy + 1e-7f));
        float sy = 0;
        for (int i = 0; i < NFRM; ++i)
            sy += fminf(alpha * yl[w + i], BETA_F * xl[w + i]);
        float mx = sx * (1.0f / NFRM), my = sy * (1.0f / NFRM);
        float cxx = 0, cyy = 0, cxy = 0;
        for (int i = 0; i < NFRM; ++i) {
            float dx = xl[w + i] - mx;
            float dy = fminf(alpha * yl[w + i], BETA_F * xl[w + i]) - my;
            cxx += dx * dx; cyy += dy * dy; cxy += dx * dy;
        }
        loc += (double)cxy / sqrt((double)cxx * (double)cyy);
    }
    red[tid] = loc;
    __syncthreads();
    for (int s = 128; s > 0; s >>= 1) {
        if (tid < s) red[tid] += red[tid + s];
        __syncthreads();
    }
    if (tid == 0) partials[b * NB + k] = red[0];
}

// ---------- K3: final deterministic reduction ----------
__global__ void k_final(const double* __restrict__ partials, int NB, float* __restrict__ out) {
    __shared__ double red[256];
    const int tid = threadIdx.x;
    const int n = NBATCH * NB;
    double s = 0.0;
    for (int i = tid; i < n; i += 256) s += partials[i];
    red[tid] = s;
    __syncthreads();
    for (int st = 128; st > 0; st >>= 1) {
        if (tid < st) red[tid] += red[tid + st];
        __syncthreads();
    }
    if (tid == 0) out[0] = (float)(-red[0] / ((double)NBATCH * NB * NWIN));
}

extern "C" void kernel_launch(void* const* d_in, const int* in_sizes, int n_in,
                              void* d_out, int out_size, void* d_ws, size_t ws_size,
                              hipStream_t stream) {
    const float* pred   = (const float*)d_in[0];
    const float* targ   = (const float*)d_in[1];
    const float* fftmat = (const float*)d_in[3];
    const float* oct    = (const float*)d_in[4];
    const int NB = in_sizes[4] / NROWS;   // 15

    char* ws = (char*)d_ws;
    int*      hdr   = (int*)ws;                          // 1 KB
    ushort_t* wpack = (ushort_t*)(ws + 1024);            // 147456 shorts = 294912 B
    size_t o1 = 1024 + (size_t)KSTEPS * TILES * 2 * 512 * 2;
    size_t xsz = (size_t)NBATCH * NB_MAX * NUMF * 4;
    float*  xbuf = (float*)(ws + o1);
    float*  ybuf = (float*)(ws + o1 + xsz);
    double* partials = (double*)(ws + o1 + 2 * xsz);

    hipLaunchKernelGGL(k_scan, dim3(1), dim3(256), 0, stream, oct, NB, hdr);
    hipLaunchKernelGGL(k_prep, dim3(288), dim3(256), 0, stream, fftmat, wpack);
    hipLaunchKernelGGL(k_probe, dim3(512), dim3(768), 0, stream, xbuf);
    hipLaunchKernelGGL(k_stft, dim3(256), dim3(768), 0, stream,
                       targ, pred, wpack, hdr, xbuf, ybuf, NB);
    hipLaunchKernelGGL(k_corr, dim3(NB, NBATCH), dim3(256), 0, stream, xbuf, ybuf, NB, partials);
    hipLaunchKernelGGL(k_final, dim3(1), dim3(256), 0, stream, partials, NB, (float*)d_out);
}

// Round 19
// 98.896 us; speedup vs baseline: 3.5702x; 1.0684x over previous
//
#include <hip/hip_runtime.h>
#include <math.h>

#define SIG_L 128000
#define NBATCH 64
#define NROWS 257
#define HOP 128
#define NUMF 999
#define NFRM 30
#define NWIN 969
#define NB_MAX 16
#define FBINS 160          // kmap entries (>= 144 used bins)
#define TILES 9            // M = 288 rows = 144 bins x (re,im)
#define KSTEPS 16
#define FPBX 256           // frames per task (four 64-columns)
#define AKB 18432          // bytes per A kk-chunk (9 tiles x 2 planes x 1024B)
#define BCH 4112           // B 16-byte chunks: (255*128+256)/8 = 4112
#define SMEMSZ (2 * AKB + BCH * 16 + NB_MAX * FPBX * 4 + 640)
#define BETA_F 6.623413251903491f  // 1 + 10^(15/20)

typedef __attribute__((ext_vector_type(8))) short short8;
typedef __attribute__((ext_vector_type(16))) float f32x16;
typedef unsigned short ushort_t;

// RNE split of fp32 into bf16 hi + bf16 lo (hi RNE; rem = v - hi exact in fp32)
__device__ inline ushort_t bf_hi_rne(float v, float* rem) {
    unsigned u = __float_as_uint(v);
    unsigned hr = (u + 0x7FFFu + ((u >> 16) & 1u)) & 0xFFFF0000u;
    *rem = v - __uint_as_float(hr);
    return (ushort_t)(hr >> 16);
}
__device__ inline ushort_t bf_rne(float v) {
    unsigned u = __float_as_uint(v);
    return (ushort_t)((u + 0x7FFFu + ((u >> 16) & 1u)) >> 16);
}

__device__ inline void gll16(const void* g, void* l) {
    __builtin_amdgcn_global_load_lds(
        (const __attribute__((address_space(1))) unsigned int*)g,
        (__attribute__((address_space(3))) unsigned int*)l, 16, 0, 0);
}

// ---------- K0: merged setup. block 0: octmat scan. blocks 1..288: weight pack ----------
__global__ void k_setup(const float* __restrict__ oct, const float* __restrict__ fftmat,
                        int NB, int* __restrict__ hdr, ushort_t* __restrict__ wpack) {
    const int tid = threadIdx.x;
    if (blockIdx.x == 0) {
        __shared__ int smin[16], smax[16];
        if (tid < NB) { smin[tid] = 0x7fffffff; smax[tid] = -1; }
        __syncthreads();
        for (int idx = tid; idx < NB * NROWS; idx += blockDim.x) {
            int k = idx / NROWS, f = idx % NROWS;
            if (oct[idx] != 0.0f) { atomicMin(&smin[k], f); atomicMax(&smax[k], f); }
        }
        __syncthreads();
        if (tid < FBINS) {
            int kid = -1;
            for (int k = 0; k < NB; ++k)
                if (smax[k] >= 0 && tid >= smin[k] && tid <= smax[k]) kid = k;
            hdr[32 + tid] = kid;
        }
        return;
    }
    // weight pack: wpack[((kk*9 + t)*2 + p)*512 + l*8 + e]; p: 0=hi 1=lo
    const int bx = blockIdx.x - 1;      // 0..287
    for (int u = 0; u < 2; ++u) {
        int idx = bx * 512 + u * 256 + tid;     // < 147456
        int e = idx & 7, l = (idx >> 3) & 63, p = (idx >> 9) & 1;
        int tt = (idx >> 10) % TILES, kk = (idx >> 10) / TILES;
        int row32 = l & 31, kq = l >> 5;
        int bin = tt * 16 + (row32 >> 1);
        int part = row32 & 1;
        int k = kk * 16 + kq * 8 + e;
        float v = fftmat[(size_t)(part ? (NROWS + bin) : bin) * 512 + 128 + k];
        float rem; ushort_t hb = bf_hi_rne(v, &rem);
        wpack[idx] = p ? bf_rne(rem) : hb;
    }
}

// ---------- K1: persistent MFMA STFT (2 tasks/block) — r18 structure, unchanged ----------
__global__ __launch_bounds__(768, 3) void k_stft(
    const float* __restrict__ targ, const float* __restrict__ pred,
    const ushort_t* __restrict__ wpack, const int* __restrict__ hdr,
    float* __restrict__ xbuf, float* __restrict__ ybuf, int NB) {
    __shared__ __align__(16) char smem[SMEMSZ];
    ushort_t* As    = (ushort_t*)smem;
    char*     Bs    = smem + 2 * AKB;
    float*    bacc  = (float*)(smem + 2 * AKB + BCH * 16);
    int*      kmapS = (int*)(smem + 2 * AKB + BCH * 16 + NB_MAX * FPBX * 4);

    const int tid = threadIdx.x;
    const int lane = tid & 63;
    const int wv = __builtin_amdgcn_readfirstlane(tid >> 6); // 0..11
    const int mg  = wv >> 2;
    const int col = wv & 3;
    const int tbase = mg * 3;
    const int jloc = lane & 31, kq = lane >> 5;

    for (int i = tid; i < FBINS; i += 768) kmapS[i] = hdr[32 + i];

#pragma unroll 1
    for (int task = 0; task < 2; ++task) {
        const int t = (int)blockIdx.x + 256 * task;
        const int z = t & 1, b = (t >> 1) & 63, tile = (t >> 7) & 3;
        const int t0 = tile * FPBX;
        const float* __restrict__ sig = z ? pred : targ;
        float* __restrict__ out = z ? ybuf : xbuf;
        const size_t boff = (size_t)b * SIG_L;

        if (task) __syncthreads();
        for (int i = tid; i < NB_MAX * FPBX; i += 768) bacc[i] = 0.0f;

        // ---- B stage: 12 loads issued up-front (branchless), then cvt+swz writes
        const long sbase = (long)t0 * HOP;
        float4 xr[12];
#pragma unroll
        for (int u = 0; u < 6; ++u) {
            const int c = tid + u * 768;
            const long g0 = sbase + (long)c * 8;
            const bool full = (c < BCH) && (g0 + 8 <= SIG_L);
            const long gc = full ? g0 : 0;
            const float* p = sig + boff + gc;
            float4 a0 = *(const float4*)(p);
            float4 a1 = *(const float4*)(p + 4);
            if (!full) { a0 = (float4){0,0,0,0}; a1 = (float4){0,0,0,0}; }
            xr[2*u] = a0; xr[2*u+1] = a1;
        }
#pragma unroll
        for (int u = 0; u < 6; ++u) {
            const int c = tid + u * 768;
            if (c < BCH) {
                short8 sv;
                sv[0]=(short)bf_rne(xr[2*u].x);   sv[1]=(short)bf_rne(xr[2*u].y);
                sv[2]=(short)bf_rne(xr[2*u].z);   sv[3]=(short)bf_rne(xr[2*u].w);
                sv[4]=(short)bf_rne(xr[2*u+1].x); sv[5]=(short)bf_rne(xr[2*u+1].y);
                sv[6]=(short)bf_rne(xr[2*u+1].z); sv[7]=(short)bf_rne(xr[2*u+1].w);
                int byte = c * 16;
                byte ^= ((byte >> 8) & 0xF) << 4;
                *(short8*)(Bs + byte) = sv;
            }
        }
        // ---- A stage kk=0 into As[0] ----
        {
            const char* gsrc = (const char*)wpack;
            for (int j = wv; j < 18; j += 12)
                gll16(gsrc + j * 1024 + lane * 16, smem + j * 1024);
        }
        __syncthreads();

        f32x16 acc[3][2];
#pragma unroll
        for (int g = 0; g < 3; ++g)
#pragma unroll
            for (int bt = 0; bt < 2; ++bt)
#pragma unroll
                for (int e = 0; e < 16; ++e) acc[g][bt][e] = 0.0f;

        int cur = 0;
#pragma unroll 1
        for (int kk = 0; kk < KSTEPS; ++kk) {
            if (kk < KSTEPS - 1) {
                const char* gsrc = (const char*)wpack + (size_t)(kk + 1) * AKB;
                char* ldst = smem + (cur ^ 1) * AKB;
                for (int j = wv; j < 18; j += 12)
                    gll16(gsrc + j * 1024 + lane * 16, ldst + j * 1024);
            }
            short8 S[2];
#pragma unroll
            for (int bt = 0; bt < 2; ++bt) {
                const int fl = col * 64 + bt * 32 + jloc;
                int byte = fl * 256 + kk * 32 + kq * 16;
                byte ^= ((byte >> 8) & 0xF) << 4;
                S[bt] = *(const short8*)(Bs + byte);
            }
            const ushort_t* ab = As + cur * (AKB / 2) + tbase * 1024 + lane * 8;
            __builtin_amdgcn_s_setprio(1);
#pragma unroll
            for (int g = 0; g < 3; ++g) {
                short8 Ah = *(const short8*)(ab + g * 1024);
                short8 Al = *(const short8*)(ab + g * 1024 + 512);
                acc[g][0] = __builtin_amdgcn_mfma_f32_32x32x16_bf16(Ah, S[0], acc[g][0], 0, 0, 0);
                acc[g][1] = __builtin_amdgcn_mfma_f32_32x32x16_bf16(Ah, S[1], acc[g][1], 0, 0, 0);
                acc[g][0] = __builtin_amdgcn_mfma_f32_32x32x16_bf16(Al, S[0], acc[g][0], 0, 0, 0);
                acc[g][1] = __builtin_amdgcn_mfma_f32_32x32x16_bf16(Al, S[1], acc[g][1], 0, 0, 0);
            }
            __builtin_amdgcn_s_setprio(0);
            __syncthreads();
            cur ^= 1;
        }

        // ---- epilogue: energies -> band accumulate -> global ----
#pragma unroll
        for (int g = 0; g < 3; ++g) {
#pragma unroll
            for (int bt = 0; bt < 2; ++bt) {
                const int fl = col * 64 + bt * 32 + jloc;
                float run = 0.0f; int runk = -1;
#pragma unroll
                for (int rr = 0; rr < 8; ++rr) {
                    const int m = (rr & 1) + 4 * (rr >> 1) + 2 * kq;
                    const int kid = kmapS[(tbase + g) * 16 + m];
                    const float vr = acc[g][bt][rr * 2], vi = acc[g][bt][rr * 2 + 1];
                    const float e = vr * vr + vi * vi;
                    if (kid != runk) {
                        if (runk >= 0) atomicAdd(&bacc[runk * FPBX + fl], run);
                        run = 0.0f; runk = kid;
                    }
                    if (kid >= 0) run += e;
                }
                if (runk >= 0) atomicAdd(&bacc[runk * FPBX + fl], run);
            }
        }
        __syncthreads();
        for (int idx = tid; idx < NB * FPBX; idx += 768) {
            int k = idx >> 8, tt = idx & (FPBX - 1);
            int tg = t0 + tt;
            if (tg < NUMF)
                out[((size_t)b * NB + k) * NUMF + tg] = bacc[k * FPBX + tt];
        }
    }
}

// ---------- K2: sliding-window correlations, register-windowed ----------
// Each thread: 4 CONSECUTIVE windows; its 33-sample x/y span copied to registers
// once (static full-unroll indexing) -> LDS reads drop 180/window -> ~17/window.
// Inner math identical to reference (3 centered loops) -> numerics unchanged.
__global__ __launch_bounds__(256) void k_corr(const float* __restrict__ xbuf,
                                              const float* __restrict__ ybuf,
                                              int NB, double* __restrict__ partials) {
    const int k = blockIdx.x, b = blockIdx.y;
    const long roff = ((long)b * NB + k) * NUMF;
    __shared__ float xl[NUMF], yl[NUMF];
    __shared__ double red[256];
    const int tid = threadIdx.x;
    for (int i = tid; i < NUMF; i += 256) {
        xl[i] = sqrtf(xbuf[roff + i]);
        yl[i] = sqrtf(ybuf[roff + i]);
    }
    __syncthreads();

    const int w0 = tid * 4;                 // windows w0..w0+3
    float xr[33], yr[33];
#pragma unroll
    for (int i = 0; i < 33; ++i) {
        int idx = w0 + i; idx = (idx < NUMF) ? idx : (NUMF - 1);
        xr[i] = xl[idx]; yr[i] = yl[idx];
    }
    double loc = 0.0;
#pragma unroll
    for (int j = 0; j < 4; ++j) {
        const int w = w0 + j;
        if (w < NWIN) {
            float sx = 0, sxx = 0, syy = 0;
#pragma unroll
            for (int i = 0; i < NFRM; ++i) {
                float xv = xr[j + i], yv = yr[j + i];
                sx += xv; sxx += xv * xv; syy += yv * yv;
            }
            float alpha = sqrtf(sxx / (syy + 1e-7f));
            float sy = 0;
#pragma unroll
            for (int i = 0; i < NFRM; ++i)
                sy += fminf(alpha * yr[j + i], BETA_F * xr[j + i]);
            float mx = sx * (1.0f / NFRM), my = sy * (1.0f / NFRM);
            float cxx = 0, cyy = 0, cxy = 0;
#pragma unroll
            for (int i = 0; i < NFRM; ++i) {
                float dx = xr[j + i] - mx;
                float dy = fminf(alpha * yr[j + i], BETA_F * xr[j + i]) - my;
                cxx += dx * dx; cyy += dy * dy; cxy += dx * dy;
            }
            loc += (double)cxy / sqrt((double)cxx * (double)cyy);
        }
    }
    red[tid] = loc;
    __syncthreads();
    for (int s = 128; s > 0; s >>= 1) {
        if (tid < s) red[tid] += red[tid + s];
        __syncthreads();
    }
    if (tid == 0) partials[b * NB + k] = red[0];
}

// ---------- K3: final deterministic reduction ----------
__global__ void k_final(const double* __restrict__ partials, int NB, float* __restrict__ out) {
    __shared__ double red[256];
    const int tid = threadIdx.x;
    const int n = NBATCH * NB;
    double s = 0.0;
    for (int i = tid; i < n; i += 256) s += partials[i];
    red[tid] = s;
    __syncthreads();
    for (int st = 128; st > 0; st >>= 1) {
        if (tid < st) red[tid] += red[tid + st];
        __syncthreads();
    }
    if (tid == 0) out[0] = (float)(-red[0] / ((double)NBATCH * NB * NWIN));
}

extern "C" void kernel_launch(void* const* d_in, const int* in_sizes, int n_in,
                              void* d_out, int out_size, void* d_ws, size_t ws_size,
                              hipStream_t stream) {
    const float* pred   = (const float*)d_in[0];
    const float* targ   = (const float*)d_in[1];
    const float* fftmat = (const float*)d_in[3];
    const float* oct    = (const float*)d_in[4];
    const int NB = in_sizes[4] / NROWS;   // 15

    char* ws = (char*)d_ws;
    int*      hdr   = (int*)ws;                          // 1 KB
    ushort_t* wpack = (ushort_t*)(ws + 1024);            // 147456 shorts = 294912 B
    size_t o1 = 1024 + (size_t)KSTEPS * TILES * 2 * 512 * 2;
    size_t xsz = (size_t)NBATCH * NB_MAX * NUMF * 4;
    float*  xbuf = (float*)(ws + o1);
    float*  ybuf = (float*)(ws + o1 + xsz);
    double* partials = (double*)(ws + o1 + 2 * xsz);

    hipLaunchKernelGGL(k_setup, dim3(289), dim3(256), 0, stream, oct, fftmat, NB, hdr, wpack);
    hipLaunchKernelGGL(k_stft, dim3(256), dim3(768), 0, stream,
                       targ, pred, wpack, hdr, xbuf, ybuf, NB);
    hipLaunchKernelGGL(k_corr, dim3(NB, NBATCH), dim3(256), 0, stream, xbuf, ybuf, NB, partials);
    hipLaunchKernelGGL(k_final, dim3(1), dim3(256), 0, stream, partials, NB, (float*)d_out);
}